// Round 1
// baseline (168.700 us; speedup 1.0000x reference)
//
#include <hip/hip_runtime.h>

#define BATCH   1024
#define GROUPS  512
#define ARITY   4
#define OUT_DIM 64

// One thread computes one float4 (4 consecutive d's) of out[b][g][:].
// 16 threads per (b,g); threads within a wave cover 4 consecutive (b,g) pairs,
// so X loads hit one cache line and the output store is 1 KiB contiguous.
__global__ __launch_bounds__(256) void hoact_kernel(
    const float4* __restrict__ X4,   // [B*G]           (ARITY=4 floats -> one float4)
    const float4* __restrict__ P4,   // [G * 16 * 16]   (16 vertices x 64 floats = 16 float4 per row)
    float4*       __restrict__ O4)   // [B*G*16]
{
    const int tid = blockIdx.x * blockDim.x + threadIdx.x;  // 0 .. B*G*16-1
    const int t   = tid & 15;        // which float4 within D=64
    const int bg  = tid >> 4;        // b*GROUPS + g
    const int g   = bg & (GROUPS - 1);

    const float4 x = X4[bg];
    float v0 = x.x, v1 = x.y, v2 = x.z, v3 = x.w;
    int   i0 = 0,   i1 = 1,   i2 = 2,   i3 = 3;

    // Predicated 5-comparator sorting network, ascending, tracks source index.
#define CSWAP(a, b, ia, ib)                         \
    {                                               \
        const bool sw = (a) > (b);                  \
        const float ta = (a), tb = (b);             \
        const int  tia = (ia), tib = (ib);          \
        (a)  = sw ? tb  : ta;  (b)  = sw ? ta  : tb;  \
        (ia) = sw ? tib : tia; (ib) = sw ? tia : tib; \
    }
    CSWAP(v0, v1, i0, i1);
    CSWAP(v2, v3, i2, i3);
    CSWAP(v0, v2, i0, i2);
    CSWAP(v1, v3, i1, i3);
    CSWAP(v1, v2, i1, i2);
#undef CSWAP

    // barycentric coefficients: smallest value, then successive gaps
    const float c0 = v0;
    const float c1 = v1 - v0;
    const float c2 = v2 - v1;
    const float c3 = v3 - v2;

    // vertex indices: reversed cumulative sum of 2^index
    const int e3 = 1 << i3;
    const int e2 = e3 + (1 << i2);
    const int e1 = e2 + (1 << i1);
    // e0 == 15 always (sum of all four bits)

    const float4* base = P4 + (size_t)g * (16 * 16) + t;
    const float4 p0 = base[15 * 16];
    const float4 p1 = base[e1 * 16];
    const float4 p2 = base[e2 * 16];
    const float4 p3 = base[e3 * 16];

    float4 o;
    o.x = c0 * p0.x + c1 * p1.x + c2 * p2.x + c3 * p3.x;
    o.y = c0 * p0.y + c1 * p1.y + c2 * p2.y + c3 * p3.y;
    o.z = c0 * p0.z + c1 * p1.z + c2 * p2.z + c3 * p3.z;
    o.w = c0 * p0.w + c1 * p1.w + c2 * p2.w + c3 * p3.w;

    O4[tid] = o;
}

extern "C" void kernel_launch(void* const* d_in, const int* in_sizes, int n_in,
                              void* d_out, int out_size, void* d_ws, size_t ws_size,
                              hipStream_t stream) {
    const float4* X4 = (const float4*)d_in[0];   // X: [1024, 512, 4] fp32
    const float4* P4 = (const float4*)d_in[1];   // params: [512, 16, 64] fp32
    float4*       O4 = (float4*)d_out;           // out: [1024, 512, 64] fp32

    const int total_threads = BATCH * GROUPS * (OUT_DIM / 4);  // 8,388,608
    const int block = 256;
    const int grid  = total_threads / block;                    // 32,768

    hipLaunchKernelGGL(hoact_kernel, dim3(grid), dim3(block), 0, stream,
                       X4, P4, O4);
}

// Round 2
// 163.307 us; speedup vs baseline: 1.0330x; 1.0330x over previous
//
#include <hip/hip_runtime.h>

#define BATCH   1024
#define GROUPS  512
#define ARITY   4
#define OUT_DIM 64

// 8 threads per (b,g); thread t computes output float4's t and t+8.
// Wave lanes: 8 consecutive lanes share a bg -> stores are 8 runs of 128 B
// (fully coalesced); X load touches 2 cache lines per wave.
//
// Sort trick: the 2-bit source index is packed into the mantissa LSBs of each
// value (<= 3 ULP perturbation, negligible vs the 0.485 absmax threshold), so
// each comparator of the 5-comparator network is just fmin/fmax. The index is
// recovered from the sorted value's low 2 bits. Exact ties produce a zero gap
// coefficient, so tie-order mismatch vs stable argsort is harmless.
__global__ __launch_bounds__(256) void hoact_kernel(
    const float4* __restrict__ X4,   // [B*G]
    const float4* __restrict__ P4,   // [G * 16 * 16]  (16 vertices x 16 float4)
    float4*       __restrict__ O4)   // [B*G*16]
{
    const int tid = blockIdx.x * blockDim.x + threadIdx.x;  // 0 .. B*G*8-1
    const int t   = tid & 7;         // which float4 pair within D=64
    const int bg  = tid >> 3;        // b*GROUPS + g
    const int g   = bg & (GROUPS - 1);

    const float4 x = X4[bg];

    // pack index into mantissa LSBs
    float v0 = __uint_as_float((__float_as_uint(x.x) & ~3u) | 0u);
    float v1 = __uint_as_float((__float_as_uint(x.y) & ~3u) | 1u);
    float v2 = __uint_as_float((__float_as_uint(x.z) & ~3u) | 2u);
    float v3 = __uint_as_float((__float_as_uint(x.w) & ~3u) | 3u);

#define CSWAP(a, b)                                  \
    {                                                \
        const float lo = fminf((a), (b));            \
        const float hi = fmaxf((a), (b));            \
        (a) = lo; (b) = hi;                          \
    }
    CSWAP(v0, v1);
    CSWAP(v2, v3);
    CSWAP(v0, v2);
    CSWAP(v1, v3);
    CSWAP(v1, v2);
#undef CSWAP

    const int i1 = __float_as_uint(v1) & 3;
    const int i2 = __float_as_uint(v2) & 3;
    const int i3 = __float_as_uint(v3) & 3;

    // barycentric coefficients: smallest value, then successive gaps
    const float c0 = v0;
    const float c1 = v1 - v0;
    const float c2 = v2 - v1;
    const float c3 = v3 - v2;

    // vertex indices: reversed cumulative sum of 2^index; e0 == 15 always
    const int e3 = 1 << i3;
    const int e2 = e3 + (1 << i2);
    const int e1 = e2 + (1 << i1);

    const float4* base = P4 + (size_t)g * 256 + t;
    const float4 p0a = base[15 * 16];
    const float4 p0b = base[15 * 16 + 8];
    const float4 p1a = base[e1 * 16];
    const float4 p1b = base[e1 * 16 + 8];
    const float4 p2a = base[e2 * 16];
    const float4 p2b = base[e2 * 16 + 8];
    const float4 p3a = base[e3 * 16];
    const float4 p3b = base[e3 * 16 + 8];

    float4 oa, ob;
    oa.x = c0 * p0a.x + c1 * p1a.x + c2 * p2a.x + c3 * p3a.x;
    oa.y = c0 * p0a.y + c1 * p1a.y + c2 * p2a.y + c3 * p3a.y;
    oa.z = c0 * p0a.z + c1 * p1a.z + c2 * p2a.z + c3 * p3a.z;
    oa.w = c0 * p0a.w + c1 * p1a.w + c2 * p2a.w + c3 * p3a.w;
    ob.x = c0 * p0b.x + c1 * p1b.x + c2 * p2b.x + c3 * p3b.x;
    ob.y = c0 * p0b.y + c1 * p1b.y + c2 * p2b.y + c3 * p3b.y;
    ob.z = c0 * p0b.z + c1 * p1b.z + c2 * p2b.z + c3 * p3b.z;
    ob.w = c0 * p0b.w + c1 * p1b.w + c2 * p2b.w + c3 * p3b.w;

    O4[bg * 16 + t]     = oa;
    O4[bg * 16 + t + 8] = ob;
}

extern "C" void kernel_launch(void* const* d_in, const int* in_sizes, int n_in,
                              void* d_out, int out_size, void* d_ws, size_t ws_size,
                              hipStream_t stream) {
    const float4* X4 = (const float4*)d_in[0];   // X: [1024, 512, 4] fp32
    const float4* P4 = (const float4*)d_in[1];   // params: [512, 16, 64] fp32
    float4*       O4 = (float4*)d_out;           // out: [1024, 512, 64] fp32

    const int total_threads = BATCH * GROUPS * (OUT_DIM / 8);  // 4,194,304
    const int block = 256;
    const int grid  = total_threads / block;                    // 16,384

    hipLaunchKernelGGL(hoact_kernel, dim3(grid), dim3(block), 0, stream,
                       X4, P4, O4);
}

// Round 3
// 145.265 us; speedup vs baseline: 1.1613x; 1.1242x over previous
//
#include <hip/hip_runtime.h>

#define BATCH   1024
#define GROUPS  512
#define OUT_DIM 64

// Row stride in LDS words: 64 data + 4 pad. 272 B/row: keeps 16 B alignment
// for ds_read_b128 and shifts each row's bank phase by 4, so the 8 bg-groups
// of a wave (reading data-dependent rows) rarely pile onto the same banks.
#define ROW_WORDS 68

// One block = one group g x 128 batches. params[g] (16 rows x 64 f32 = 4 KiB)
// is staged in LDS once and reused by all 128 batches (the b-reuse is 1024x
// across the grid), replacing ~537 MB of global gather traffic with LDS reads.
// 8 lanes per (b,g): lane t computes output float4's t and t+8.
__global__ __launch_bounds__(256) void hoact_kernel(
    const float4* __restrict__ X4,   // [B*G]       (4 f32 -> one float4)
    const float4* __restrict__ P4,   // [G*256]     (16 rows x 16 float4)
    float4*       __restrict__ O4)   // [B*G*16]
{
    __shared__ float tbl[16 * ROW_WORDS];

    const int g     = blockIdx.x >> 3;       // 0..511
    const int chunk = blockIdx.x & 7;        // 0..7
    const int b0    = chunk * 128;
    const int tid   = threadIdx.x;           // 0..255

    // ---- stage params[g] into LDS (row-padded) ----
    {
        const float4 v = P4[g * 256 + tid];          // coalesced 4 KiB
        const int row = tid >> 4, c4 = tid & 15;
        *(float4*)&tbl[row * ROW_WORDS + c4 * 4] = v;  // ds_write_b128
    }

    const int t       = tid & 7;             // float4 column within D=64
    const int bl_base = tid >> 3;            // 0..31

    // ---- prefetch X for all 4 passes (independent loads, hide latency) ----
    float4 xv[4];
#pragma unroll
    for (int p = 0; p < 4; ++p) {
        const int b = b0 + p * 32 + bl_base;
        xv[p] = X4[b * GROUPS + g];          // 8 lanes broadcast one address
    }

    __syncthreads();

#pragma unroll
    for (int p = 0; p < 4; ++p) {
        const int b = b0 + p * 32 + bl_base;
        const float4 x = xv[p];

        // pack 2-bit source index into mantissa LSBs (<=3 ULP, harmless vs
        // 0.485 threshold); sort via fmin/fmax network; ties -> zero gap coef.
        float v0 = __uint_as_float((__float_as_uint(x.x) & ~3u) | 0u);
        float v1 = __uint_as_float((__float_as_uint(x.y) & ~3u) | 1u);
        float v2 = __uint_as_float((__float_as_uint(x.z) & ~3u) | 2u);
        float v3 = __uint_as_float((__float_as_uint(x.w) & ~3u) | 3u);

#define CSWAP(a, b_)                                 \
        {                                            \
            const float lo = fminf((a), (b_));       \
            const float hi = fmaxf((a), (b_));       \
            (a) = lo; (b_) = hi;                     \
        }
        CSWAP(v0, v1);
        CSWAP(v2, v3);
        CSWAP(v0, v2);
        CSWAP(v1, v3);
        CSWAP(v1, v2);
#undef CSWAP

        const int i1 = __float_as_uint(v1) & 3;
        const int i2 = __float_as_uint(v2) & 3;
        const int i3 = __float_as_uint(v3) & 3;

        const float c0 = v0;
        const float c1 = v1 - v0;
        const float c2 = v2 - v1;
        const float c3 = v3 - v2;

        const int e3 = 1 << i3;
        const int e2 = e3 + (1 << i2);
        const int e1 = e2 + (1 << i1);
        // e0 == 15 always

        const float4 p0a = *(const float4*)&tbl[15 * ROW_WORDS + t * 4];
        const float4 p0b = *(const float4*)&tbl[15 * ROW_WORDS + (t + 8) * 4];
        const float4 p1a = *(const float4*)&tbl[e1 * ROW_WORDS + t * 4];
        const float4 p1b = *(const float4*)&tbl[e1 * ROW_WORDS + (t + 8) * 4];
        const float4 p2a = *(const float4*)&tbl[e2 * ROW_WORDS + t * 4];
        const float4 p2b = *(const float4*)&tbl[e2 * ROW_WORDS + (t + 8) * 4];
        const float4 p3a = *(const float4*)&tbl[e3 * ROW_WORDS + t * 4];
        const float4 p3b = *(const float4*)&tbl[e3 * ROW_WORDS + (t + 8) * 4];

        float4 oa, ob;
        oa.x = c0 * p0a.x + c1 * p1a.x + c2 * p2a.x + c3 * p3a.x;
        oa.y = c0 * p0a.y + c1 * p1a.y + c2 * p2a.y + c3 * p3a.y;
        oa.z = c0 * p0a.z + c1 * p1a.z + c2 * p2a.z + c3 * p3a.z;
        oa.w = c0 * p0a.w + c1 * p1a.w + c2 * p2a.w + c3 * p3a.w;
        ob.x = c0 * p0b.x + c1 * p1b.x + c2 * p2b.x + c3 * p3b.x;
        ob.y = c0 * p0b.y + c1 * p1b.y + c2 * p2b.y + c3 * p3b.y;
        ob.z = c0 * p0b.z + c1 * p1b.z + c2 * p2b.z + c3 * p3b.z;
        ob.w = c0 * p0b.w + c1 * p1b.w + c2 * p2b.w + c3 * p3b.w;

        // out[b][g][:]: 8 lanes -> 128 B contiguous runs, b-stride 128 KiB
        const int o_idx = b * (GROUPS * 16) + g * 16 + t;
        O4[o_idx]     = oa;
        O4[o_idx + 8] = ob;
    }
}

extern "C" void kernel_launch(void* const* d_in, const int* in_sizes, int n_in,
                              void* d_out, int out_size, void* d_ws, size_t ws_size,
                              hipStream_t stream) {
    const float4* X4 = (const float4*)d_in[0];   // X: [1024, 512, 4] fp32
    const float4* P4 = (const float4*)d_in[1];   // params: [512, 16, 64] fp32
    float4*       O4 = (float4*)d_out;           // out: [1024, 512, 64] fp32

    const int grid = GROUPS * 8;                 // 4096 blocks
    hipLaunchKernelGGL(hoact_kernel, dim3(grid), dim3(256), 0, stream,
                       X4, P4, O4);
}